// Round 9
// baseline (404.594 us; speedup 1.0000x reference)
//
#include <hip/hip_runtime.h>
#include <math.h>

#define NN 20000
#define EE 400000
#define FIN 256
#define HH 16
#define CC 32
#define HC 512    // H*C per conv
#define HW 1024   // h12 row width (conv1 | conv2)
#define HIDN 128
#define OUTC 32
#define WT 1024   // wtc rows (W1^T | W2^T)
#define CAPD 64   // per-node LDS edge capacity (deg ~ Poisson(20), P(>64)~1e-16)

typedef unsigned short u16;
typedef __attribute__((ext_vector_type(8))) short short8v;
typedef __attribute__((ext_vector_type(4))) float f32x4;

__device__ inline u16 f2bf(float f) {
  unsigned u = __builtin_bit_cast(unsigned, f);
  unsigned r = (u + 0x7fffu + ((u >> 16) & 1u)) >> 16;
  return (u16)r;
}
__device__ inline float bf2f(u16 b) {
  unsigned u = ((unsigned)b) << 16;
  return __builtin_bit_cast(float, u);
}

__device__ __forceinline__ void gload16(const u16* g, u16* l) {
  __builtin_amdgcn_global_load_lds(
      (const __attribute__((address_space(1))) unsigned int*)g,
      (__attribute__((address_space(3))) unsigned int*)l, 16, 0, 0);
}

// ------------------------------------------- merged converts + edge histogram
__global__ void k_prep_hist(const float* __restrict__ x, u16* __restrict__ xb,
                            const float* __restrict__ W1, const float* __restrict__ W2,
                            u16* __restrict__ wtc,
                            const float* __restrict__ L1, u16* __restrict__ lt1,
                            const float* __restrict__ L2, u16* __restrict__ lt2,
                            const int* __restrict__ ei, int* __restrict__ cur) {
  int b = blockIdx.x, t = threadIdx.x;
  if (b < 2500) {
    int i = b * 256 + t;
    float4 v0 = ((const float4*)x)[i * 2];
    float4 v1 = ((const float4*)x)[i * 2 + 1];
    short8v o;
    o[0] = (short)f2bf(v0.x); o[1] = (short)f2bf(v0.y);
    o[2] = (short)f2bf(v0.z); o[3] = (short)f2bf(v0.w);
    o[4] = (short)f2bf(v1.x); o[5] = (short)f2bf(v1.y);
    o[6] = (short)f2bf(v1.z); o[7] = (short)f2bf(v1.w);
    *(short8v*)(xb + (size_t)i * 8) = o;
  } else if (b < 3524) {
    int i = (b - 2500) * 256 + t;   // [1024][256]
    int n = i >> 8, k = i & 255;
    wtc[i] = f2bf(n < 512 ? W1[k * HC + n] : W2[k * HC + (n - 512)]);
  } else if (b < 3652) {
    int i = (b - 3524) * 256 + t;   // [128][256]
    int n = i >> 8, k = i & 255;
    lt1[i] = f2bf(L1[k * HIDN + n]);
  } else if (b < 3668) {
    int i = (b - 3652) * 256 + t;   // [32][128]
    int n = i >> 7, k = i & 127;
    lt2[i] = f2bf(L2[k * OUTC + n]);
  } else {
    int e = (b - 3668) * 256 + t;
    if (e < EE) {
      atomicAdd(&cur[ei[EE + e]], 1);       // conv1 aggregates at row1
      atomicAdd(&cur[NN + ei[e]], 1);       // conv2 aggregates at row0
    }
  }
}

__device__ void scan_one(int* cur, int* off, int* part) {
  const int t = threadIdx.x;
  const int CHK = 20;
  int base = t * CHK;
  int loc[CHK];
  int s = 0;
#pragma unroll
  for (int i = 0; i < CHK; ++i) {
    int idx = base + i;
    int v = (idx < NN) ? cur[idx] : 0;
    loc[i] = s;
    s += v;
  }
  part[t] = s;
  __syncthreads();
  for (int d = 1; d < 1024; d <<= 1) {
    int v2 = (t >= d) ? part[t - d] : 0;
    __syncthreads();
    part[t] += v2;
    __syncthreads();
  }
  int cbase = part[t] - s;
#pragma unroll
  for (int i = 0; i < CHK; ++i) {
    int idx = base + i;
    if (idx < NN) {
      int o = cbase + loc[i];
      off[idx] = o;
      cur[idx] = o;
    }
  }
  if (t == 1023) off[NN] = part[1023];
}

__global__ __launch_bounds__(1024) void k_scan(int* cur, int* off1, int* off2) {
  __shared__ int part[1024];
  if (blockIdx.x == 0) scan_one(cur, off1, part);
  else                 scan_one(cur + NN, off2, part);
}

__global__ void k_scatter(const int* __restrict__ ei, int* cur,
                          int* __restrict__ adj1, int* __restrict__ adj2) {
  int e = blockIdx.x * 256 + threadIdx.x;
  if (e < EE) {
    int s1 = ei[e], d1 = ei[EE + e];
    int p1 = atomicAdd(&cur[d1], 1);
    adj1[p1] = s1;                      // conv1: message source = row0
    int p2 = atomicAdd(&cur[NN + s1], 1);
    adj2[p2] = d1;                      // conv2: message source = row1
  }
}

// ------------------------- mega GEMM: h12 = x@[W1|W2]^T + fused a_s/a_d
__global__ __launch_bounds__(256) void k_gemm_big(const u16* __restrict__ A,
                                                  const u16* __restrict__ Bt,
                                                  const float* __restrict__ as1,
                                                  const float* __restrict__ ad1,
                                                  const float* __restrict__ as2,
                                                  const float* __restrict__ ad2,
                                                  u16* __restrict__ h12,
                                                  float* __restrict__ a_sA,
                                                  float* __restrict__ a_dA) {
  __shared__ u16 As[128 * 64];
  __shared__ u16 Bs[128 * 64];
  const int hw = blockIdx.x;
  const int logical = (hw & 7) * 157 + (hw >> 3);
  const int bm = (logical >> 3) * 128, bn = logical & 7;
  const int t = threadIdx.x;
  const int lane = t & 63, wave = t >> 6;
  const int wr = (wave >> 1) * 64, wc = (wave & 1) * 64;
  const int l15 = lane & 15, l4 = lane >> 4;
  const int rloc = lane >> 3;
  const int kc_src = (lane & 7) ^ rloc;
  const int K = FIN;

  f32x4 acc[4][4] = {};
  for (int k0 = 0; k0 < K; k0 += 64) {
    __syncthreads();
#pragma unroll
    for (int q = 0; q < 4; ++q) {
      const int rblk = q * 4 + wave;
      const int r = rblk * 8 + rloc;
      gload16(A + (size_t)(bm + r) * K + k0 + kc_src * 8, As + rblk * 512);
      gload16(Bt + (size_t)(bn * 128 + r) * K + k0 + kc_src * 8, Bs + rblk * 512);
    }
    __syncthreads();
#pragma unroll
    for (int kh = 0; kh < 2; ++kh) {
      const int kc = kh * 4 + l4;
      short8v af[4], bfr[4];
#pragma unroll
      for (int i = 0; i < 4; ++i) {
        int row = wr + i * 16 + l15;
        af[i] = *(const short8v*)(As + row * 64 + (kc ^ (row & 7)) * 8);
      }
#pragma unroll
      for (int j = 0; j < 4; ++j) {
        int row = wc + j * 16 + l15;
        bfr[j] = *(const short8v*)(Bs + row * 64 + (kc ^ (row & 7)) * 8);
      }
#pragma unroll
      for (int i = 0; i < 4; ++i)
#pragma unroll
        for (int j = 0; j < 4; ++j)
          acc[i][j] = __builtin_amdgcn_mfma_f32_16x16x32_bf16(af[i], bfr[j], acc[i][j], 0, 0, 0);
    }
  }

  const int conv = bn >> 2;
#pragma unroll
  for (int i = 0; i < 4; ++i)
#pragma unroll
    for (int j = 0; j < 4; ++j)
#pragma unroll
      for (int r = 0; r < 4; ++r) {
        int row = bm + wr + i * 16 + l4 * 4 + r;
        if (row >= NN) continue;
        int colb = bn * 128 + wc + j * 16 + l15;
        h12[(size_t)row * HW + colb] = f2bf(acc[i][j][r]);
      }

  float asv[4], adv[4];
#pragma unroll
  for (int j = 0; j < 4; ++j) {
    int lc = (bn & 3) * 128 + wc + j * 16 + l15;
    int hh = lc >> 5, c = lc & 31;
    asv[j] = (conv ? as2 : as1)[hh * CC + c];
    adv[j] = (conv ? ad2 : ad1)[hh * CC + c];
  }
  const int hA = (bn & 3) * 4 + (wc >> 5);
  float* aS = a_sA + (size_t)conv * NN * HH;
  float* aD = a_dA + (size_t)conv * NN * HH;
#pragma unroll
  for (int i = 0; i < 4; ++i)
#pragma unroll
    for (int r = 0; r < 4; ++r) {
      float sAs = acc[i][0][r] * asv[0] + acc[i][1][r] * asv[1];
      float sAd = acc[i][0][r] * adv[0] + acc[i][1][r] * adv[1];
      float sBs = acc[i][2][r] * asv[2] + acc[i][3][r] * asv[3];
      float sBd = acc[i][2][r] * adv[2] + acc[i][3][r] * adv[3];
#pragma unroll
      for (int m = 1; m < 16; m <<= 1) {
        sAs += __shfl_xor(sAs, m);
        sAd += __shfl_xor(sAd, m);
        sBs += __shfl_xor(sBs, m);
        sBd += __shfl_xor(sBd, m);
      }
      int row = bm + wr + i * 16 + l4 * 4 + r;
      if (l15 == 0 && row < NN) {
        *(float2*)(aS + (size_t)row * HH + hA) = make_float2(sAs, sBs);
        *(float2*)(aD + (size_t)row * HH + hA) = make_float2(sAd, sBd);
      }
    }
}

// --------------------------- self path: out3 = elu(elu(x@lin1+b)@lin2+b)
__global__ __launch_bounds__(256) void k_self(const u16* __restrict__ A,
                                              const u16* __restrict__ lt1,
                                              const u16* __restrict__ lt2,
                                              const float* __restrict__ lin1_b,
                                              const float* __restrict__ lin2_b,
                                              float* __restrict__ outp) {
  __shared__ u16 smem[128 * 136];
  u16* As = smem;
  u16* Bs = smem + 128 * 64;
  const int t = threadIdx.x;
  const int lane = t & 63, wave = t >> 6;
  const int wr = (wave >> 1) * 64, wc = (wave & 1) * 64;
  const int bm = blockIdx.x * 128;
  const int l15 = lane & 15, l4 = lane >> 4;
  const int rloc = lane >> 3;
  const int kc_src = (lane & 7) ^ rloc;
  const int K = FIN;

  f32x4 acc[4][4] = {};
  for (int k0 = 0; k0 < K; k0 += 64) {
    __syncthreads();
#pragma unroll
    for (int q = 0; q < 4; ++q) {
      const int rblk = q * 4 + wave;
      const int r = rblk * 8 + rloc;
      gload16(A + (size_t)(bm + r) * K + k0 + kc_src * 8, As + rblk * 512);
      gload16(lt1 + (size_t)r * K + k0 + kc_src * 8, Bs + rblk * 512);
    }
    __syncthreads();
#pragma unroll
    for (int kh = 0; kh < 2; ++kh) {
      const int kc = kh * 4 + l4;
      short8v af[4], bfr[4];
#pragma unroll
      for (int i = 0; i < 4; ++i) {
        int row = wr + i * 16 + l15;
        af[i] = *(const short8v*)(As + row * 64 + (kc ^ (row & 7)) * 8);
      }
#pragma unroll
      for (int j = 0; j < 4; ++j) {
        int row = wc + j * 16 + l15;
        bfr[j] = *(const short8v*)(Bs + row * 64 + (kc ^ (row & 7)) * 8);
      }
#pragma unroll
      for (int i = 0; i < 4; ++i)
#pragma unroll
        for (int j = 0; j < 4; ++j)
          acc[i][j] = __builtin_amdgcn_mfma_f32_16x16x32_bf16(af[i], bfr[j], acc[i][j], 0, 0, 0);
    }
  }
  __syncthreads();
#pragma unroll
  for (int i = 0; i < 4; ++i)
#pragma unroll
    for (int j = 0; j < 4; ++j)
#pragma unroll
      for (int r = 0; r < 4; ++r) {
        int row = wr + i * 16 + l4 * 4 + r;
        int col = wc + j * 16 + l15;
        float v = acc[i][j][r] + lin1_b[col];
        v = v > 0.f ? v : (expf(v) - 1.f);
        smem[row * 136 + col] = f2bf(v);
      }
  __syncthreads();
  f32x4 acc2[2][2] = {};
#pragma unroll
  for (int kk = 0; kk < 4; ++kk) {
    short8v af[2], bfr[2];
#pragma unroll
    for (int i = 0; i < 2; ++i)
      af[i] = *(const short8v*)(smem + (wave * 32 + i * 16 + l15) * 136 + kk * 32 + l4 * 8);
#pragma unroll
    for (int j = 0; j < 2; ++j)
      bfr[j] = *(const short8v*)(lt2 + (size_t)(j * 16 + l15) * 128 + kk * 32 + l4 * 8);
#pragma unroll
    for (int i = 0; i < 2; ++i)
#pragma unroll
      for (int j = 0; j < 2; ++j)
        acc2[i][j] = __builtin_amdgcn_mfma_f32_16x16x32_bf16(af[i], bfr[j], acc2[i][j], 0, 0, 0);
  }
#pragma unroll
  for (int i = 0; i < 2; ++i)
#pragma unroll
    for (int j = 0; j < 2; ++j)
#pragma unroll
      for (int r = 0; r < 4; ++r) {
        int row = bm + wave * 32 + i * 16 + l4 * 4 + r;
        int col = j * 16 + l15;
        if (row < NN) {
          float v = acc2[i][j][r] + lin2_b[col];
          v = v > 0.f ? v : (expf(v) - 1.f);
          outp[(size_t)row * OUTC + col] = v;
        }
      }
}

// ---------------- XCD-sliced fused softmax+aggregation.
// Grid 80000: conv = bid/40000; hp = bid%8 (-> XCD slice, 64 channels = 2 heads);
// node = (bid%40000 / 8)*4 + wave. Each wave: 2-head softmax + 64-ch aggregation,
// partial -> part[conv*NN+node][hp][32].
__global__ __launch_bounds__(256) void k_edge2(const int* __restrict__ adj1,
                                               const int* __restrict__ off1,
                                               const int* __restrict__ adj2,
                                               const int* __restrict__ off2,
                                               const float* __restrict__ a_sA,
                                               const float* __restrict__ a_dA,
                                               const u16* __restrict__ h12,
                                               float* __restrict__ part) {
  __shared__ float exs[4][CAPD * 2];
  const int wv = threadIdx.x >> 6, lane = threadIdx.x & 63;
  int bid = blockIdx.x;
  const int conv = bid >= 40000;
  bid -= conv * 40000;
  const int hp = bid & 7;
  const int node = (bid >> 3) * 4 + wv;
  const int* __restrict__ adj = conv ? adj2 : adj1;
  const int* __restrict__ off = conv ? off2 : off1;
  const float* __restrict__ a_s = a_sA + (size_t)conv * NN * HH;
  const float* __restrict__ a_d = a_dA + (size_t)conv * NN * HH;
  float* exw = exs[wv];
  const int e0 = off[node], e1 = off[node + 1];
  const int deg = e1 - e0;
  float* pdst = part + (((size_t)conv * NN + node) * 8 + hp) * 32;

  if (deg == 0) {
    if (lane < 16) *(float2*)(pdst + lane * 2) = make_float2(0.f, 0.f);
    return;
  }

  // ---- phase A: softmax stats for heads hp*2+{0,1}; lane = j*2 + h2
  const int h2 = lane & 1, j = lane >> 1;
  const int hh = hp * 2 + h2;
  const float adh = a_d[node * HH + hh];
  float mx = -INFINITY;
  for (int p = e0 + j; p < e1; p += 32) {
    int s = adj[p];
    float a = a_s[s * HH + hh] + adh;
    a = a > 0.f ? a : 0.2f * a;
    int q = p - e0;
    if (q < CAPD) exw[q * 2 + h2] = a;
    mx = fmaxf(mx, a);
  }
#pragma unroll
  for (int m = 2; m <= 32; m <<= 1) mx = fmaxf(mx, __shfl_xor(mx, m));
  float sum = 0.f;
  for (int p = e0 + j; p < e1; p += 32) {
    int q = p - e0;
    float a;
    if (q < CAPD) {
      a = exw[q * 2 + h2];
    } else {
      int s = adj[p];
      a = a_s[s * HH + hh] + adh;
      a = a > 0.f ? a : 0.2f * a;
    }
    float e = __expf(a - mx);
    if (q < CAPD) exw[q * 2 + h2] = e;
    sum += e;
  }
#pragma unroll
  for (int m = 2; m <= 32; m <<= 1) sum += __shfl_xor(sum, m);
  __builtin_amdgcn_wave_barrier();
  __asm__ volatile("" ::: "memory");

  // ---- phase B: lane = ep*32 + l5; l5 -> channels 2*l5, 2*l5+1 of slice;
  // head-in-pair hB = l5>>4; edge parity ep.
  const int ep = lane >> 5, l5 = lane & 31;
  const int hB = l5 >> 4;
  const float invB = __shfl(1.f / ((sum + 1e-16f) * 16.f), hB);  // lanes 0/1 hold h2=0/1
  const float mxB = __shfl(mx, hB);
  const float adhB = __shfl(adh, hB);
  const u16* hbase = h12 + conv * HC + hp * 64 + l5 * 2;
  float a0 = 0.f, a1 = 0.f, b0 = 0.f, b1 = 0.f;
  int p = e0 + ep;
  if (deg <= CAPD) {
    for (; p + 2 < e1; p += 4) {
      int sA = adj[p], sB = adj[p + 2];
      float eA = exw[(p - e0) * 2 + hB];
      float eB = exw[(p + 2 - e0) * 2 + hB];
      unsigned hA = *(const unsigned*)(hbase + (size_t)sA * HW);
      unsigned hBv = *(const unsigned*)(hbase + (size_t)sB * HW);
      a0 = fmaf(eA, bf2f((u16)(hA & 0xffff)), a0);
      a1 = fmaf(eA, bf2f((u16)(hA >> 16)), a1);
      b0 = fmaf(eB, bf2f((u16)(hBv & 0xffff)), b0);
      b1 = fmaf(eB, bf2f((u16)(hBv >> 16)), b1);
    }
    if (p < e1) {
      int sA = adj[p];
      float eA = exw[(p - e0) * 2 + hB];
      unsigned hA = *(const unsigned*)(hbase + (size_t)sA * HW);
      a0 = fmaf(eA, bf2f((u16)(hA & 0xffff)), a0);
      a1 = fmaf(eA, bf2f((u16)(hA >> 16)), a1);
    }
  } else {  // rare deg > CAPD: recompute weights past capacity
    for (; p < e1; p += 2) {
      int sA = adj[p];
      int q = p - e0;
      float eA;
      if (q < CAPD) {
        eA = exw[q * 2 + hB];
      } else {
        float a = a_s[sA * HH + hp * 2 + hB] + adhB;
        a = a > 0.f ? a : 0.2f * a;
        eA = __expf(a - mxB);
      }
      unsigned hA = *(const unsigned*)(hbase + (size_t)sA * HW);
      a0 = fmaf(eA, bf2f((u16)(hA & 0xffff)), a0);
      a1 = fmaf(eA, bf2f((u16)(hA >> 16)), a1);
    }
  }
  float c0 = a0 + b0, c1 = a1 + b1;
  c0 += __shfl_xor(c0, 32);           // combine edge parities
  c1 += __shfl_xor(c1, 32);
  c0 *= invB;                         // per-head 1/(den*16)
  c1 *= invB;
  c0 += __shfl_xor(c0, 16);           // sum the 2 heads (same out channels)
  c1 += __shfl_xor(c1, 16);
  if (lane < 16) *(float2*)(pdst + lane * 2) = make_float2(c0, c1);
}

// ---------------- final: out = elu(sum_hp part + bias); 8 units/block
__global__ __launch_bounds__(256) void k_final(const float* __restrict__ part,
                                               const float* __restrict__ b1,
                                               const float* __restrict__ b2,
                                               float* __restrict__ out) {
  const int wv = threadIdx.x >> 6, lane = threadIdx.x & 63;
  const int unit = blockIdx.x * 8 + wv * 2 + (lane >> 5);  // 0..40000
  const int conv = unit >= NN;
  const int c = lane & 31;
  const float* pp = part + (size_t)unit * 8 * 32 + c;
  float s = 0.f;
#pragma unroll
  for (int hp = 0; hp < 8; ++hp) s += pp[hp * 32];
  float v = s + (conv ? b2 : b1)[c];
  v = v > 0.f ? v : (expf(v) - 1.f);
  out[(size_t)unit * OUTC + c] = v;
}

// ---------------------------------------------------------------- launch
extern "C" void kernel_launch(void* const* d_in, const int* in_sizes, int n_in,
                              void* d_out, int out_size, void* d_ws, size_t ws_size,
                              hipStream_t stream) {
  const float* x = (const float*)d_in[0];
  const int* ei = (const int*)d_in[1];
  const float* W1 = (const float*)d_in[2];
  const float* att_src1 = (const float*)d_in[3];
  const float* att_dst1 = (const float*)d_in[4];
  const float* b1 = (const float*)d_in[5];
  const float* W2 = (const float*)d_in[6];
  const float* att_src2 = (const float*)d_in[7];
  const float* att_dst2 = (const float*)d_in[8];
  const float* b2 = (const float*)d_in[9];
  const float* lin1_w = (const float*)d_in[10];
  const float* lin1_b = (const float*)d_in[11];
  const float* lin2_w = (const float*)d_in[12];
  const float* lin2_b = (const float*)d_in[13];
  float* out = (float*)d_out;  // [x_in | x_out | x_self], each N*32

  char* w = (char*)d_ws;
  u16* h12 = (u16*)w;       w += (size_t)NN * HW * 2;        // 40.96 MB
  u16* x_bf = (u16*)w;      w += (size_t)NN * FIN * 2;       // 10.24 MB
  u16* wtc = (u16*)w;       w += (size_t)WT * FIN * 2;       // 0.52 MB
  u16* lt1 = (u16*)w;       w += (size_t)HIDN * FIN * 2;
  u16* lt2 = (u16*)w;       w += (size_t)OUTC * HIDN * 2;
  float* part = (float*)w;  w += (size_t)2 * NN * 8 * 32 * 4;  // 40.96 MB
  float* a_sA = (float*)w;  w += (size_t)2 * NN * HH * 4;    // 2.56 MB
  float* a_dA = (float*)w;  w += (size_t)2 * NN * HH * 4;
  int* off1 = (int*)w;      w += (size_t)(NN + 1) * 4;
  int* off2 = (int*)w;      w += (size_t)(NN + 1) * 4;
  int* cur = (int*)w;       w += (size_t)2 * NN * 4;
  int* adj1 = (int*)w;      w += (size_t)EE * 4;
  int* adj2 = (int*)w;      w += (size_t)EE * 4;

  const int EB = (EE + 255) / 256;  // 1563

  // CSR build + converts
  hipMemsetAsync(cur, 0, (size_t)2 * NN * 4, stream);
  k_prep_hist<<<3668 + EB, 256, 0, stream>>>(x, x_bf, W1, W2, wtc, lin1_w, lt1,
                                             lin2_w, lt2, ei, cur);
  k_scan<<<2, 1024, 0, stream>>>(cur, off1, off2);
  k_scatter<<<EB, 256, 0, stream>>>(ei, cur, adj1, adj2);

  // GEMMs
  k_gemm_big<<<1256, 256, 0, stream>>>(x_bf, wtc, att_src1, att_dst1,
                                       att_src2, att_dst2, h12, a_sA, a_dA);
  k_self<<<157, 256, 0, stream>>>(x_bf, lt1, lt2, lin1_b, lin2_b,
                                  out + (size_t)2 * NN * OUTC);

  // XCD-sliced softmax+aggregation, then partial reduce
  k_edge2<<<80000, 256, 0, stream>>>(adj1, off1, adj2, off2, a_sA, a_dA,
                                     h12, part);
  k_final<<<2 * NN / 8, 256, 0, stream>>>(part, b1, b2, out);
}

// Round 10
// 275.207 us; speedup vs baseline: 1.4701x; 1.4701x over previous
//
#include <hip/hip_runtime.h>
#include <math.h>

#define NN 20000
#define EE 400000
#define FIN 256
#define HH 16
#define CC 32
#define HC 512    // channels per conv
#define H8W 1024  // h8 row width in bytes (conv1 | conv2)
#define HIDN 128
#define OUTC 32
#define WT 1024   // wtc rows (W1^T | W2^T)
#define CAPD 64   // per-node LDS edge capacity (deg ~ Poisson(20), P(>64)~1e-16)

typedef unsigned short u16;
typedef unsigned char u8;
typedef __attribute__((ext_vector_type(8))) short short8v;
typedef __attribute__((ext_vector_type(4))) float f32x4;
typedef __attribute__((ext_vector_type(2))) float f32x2;

__device__ inline u16 f2bf(float f) {
  unsigned u = __builtin_bit_cast(unsigned, f);
  unsigned r = (u + 0x7fffu + ((u >> 16) & 1u)) >> 16;
  return (u16)r;
}
__device__ inline float bf2f(u16 b) {
  unsigned u = ((unsigned)b) << 16;
  return __builtin_bit_cast(float, u);
}

__device__ __forceinline__ void gload16(const u16* g, u16* l) {
  __builtin_amdgcn_global_load_lds(
      (const __attribute__((address_space(1))) unsigned int*)g,
      (__attribute__((address_space(3))) unsigned int*)l, 16, 0, 0);
}

// fp8 (e4m3) decode of 8 packed bytes -> fma into acc[0..8)
__device__ __forceinline__ void fp8x8_fma(uint2 hv, float w, float* acc) {
  f32x2 p;
  p = __builtin_amdgcn_cvt_pk_f32_fp8(hv.x, false);
  acc[0] = fmaf(w, p.x, acc[0]); acc[1] = fmaf(w, p.y, acc[1]);
  p = __builtin_amdgcn_cvt_pk_f32_fp8(hv.x, true);
  acc[2] = fmaf(w, p.x, acc[2]); acc[3] = fmaf(w, p.y, acc[3]);
  p = __builtin_amdgcn_cvt_pk_f32_fp8(hv.y, false);
  acc[4] = fmaf(w, p.x, acc[4]); acc[5] = fmaf(w, p.y, acc[5]);
  p = __builtin_amdgcn_cvt_pk_f32_fp8(hv.y, true);
  acc[6] = fmaf(w, p.x, acc[6]); acc[7] = fmaf(w, p.y, acc[7]);
}

// ------------------------------------------- merged converts + edge histogram
__global__ void k_prep_hist(const float* __restrict__ x, u16* __restrict__ xb,
                            const float* __restrict__ W1, const float* __restrict__ W2,
                            u16* __restrict__ wtc,
                            const float* __restrict__ L1, u16* __restrict__ lt1,
                            const float* __restrict__ L2, u16* __restrict__ lt2,
                            const int* __restrict__ ei, int* __restrict__ cur) {
  int b = blockIdx.x, t = threadIdx.x;
  if (b < 2500) {
    int i = b * 256 + t;
    float4 v0 = ((const float4*)x)[i * 2];
    float4 v1 = ((const float4*)x)[i * 2 + 1];
    short8v o;
    o[0] = (short)f2bf(v0.x); o[1] = (short)f2bf(v0.y);
    o[2] = (short)f2bf(v0.z); o[3] = (short)f2bf(v0.w);
    o[4] = (short)f2bf(v1.x); o[5] = (short)f2bf(v1.y);
    o[6] = (short)f2bf(v1.z); o[7] = (short)f2bf(v1.w);
    *(short8v*)(xb + (size_t)i * 8) = o;
  } else if (b < 3524) {
    int i = (b - 2500) * 256 + t;   // [1024][256]
    int n = i >> 8, k = i & 255;
    wtc[i] = f2bf(n < 512 ? W1[k * HC + n] : W2[k * HC + (n - 512)]);
  } else if (b < 3652) {
    int i = (b - 3524) * 256 + t;   // [128][256]
    int n = i >> 8, k = i & 255;
    lt1[i] = f2bf(L1[k * HIDN + n]);
  } else if (b < 3668) {
    int i = (b - 3652) * 256 + t;   // [32][128]
    int n = i >> 7, k = i & 127;
    lt2[i] = f2bf(L2[k * OUTC + n]);
  } else {
    int e = (b - 3668) * 256 + t;
    if (e < EE) {
      atomicAdd(&cur[ei[EE + e]], 1);       // conv1 aggregates at row1
      atomicAdd(&cur[NN + ei[e]], 1);       // conv2 aggregates at row0
    }
  }
}

__device__ void scan_one(int* cur, int* off, int* part) {
  const int t = threadIdx.x;
  const int CHK = 20;
  int base = t * CHK;
  int loc[CHK];
  int s = 0;
#pragma unroll
  for (int i = 0; i < CHK; ++i) {
    int idx = base + i;
    int v = (idx < NN) ? cur[idx] : 0;
    loc[i] = s;
    s += v;
  }
  part[t] = s;
  __syncthreads();
  for (int d = 1; d < 1024; d <<= 1) {
    int v2 = (t >= d) ? part[t - d] : 0;
    __syncthreads();
    part[t] += v2;
    __syncthreads();
  }
  int cbase = part[t] - s;
#pragma unroll
  for (int i = 0; i < CHK; ++i) {
    int idx = base + i;
    if (idx < NN) {
      int o = cbase + loc[i];
      off[idx] = o;
      cur[idx] = o;
    }
  }
  if (t == 1023) off[NN] = part[1023];
}

__global__ __launch_bounds__(1024) void k_scan(int* cur, int* off1, int* off2) {
  __shared__ int part[1024];
  if (blockIdx.x == 0) scan_one(cur, off1, part);
  else                 scan_one(cur + NN, off2, part);
}

__global__ void k_scatter(const int* __restrict__ ei, int* cur,
                          int* __restrict__ adj1, int* __restrict__ adj2) {
  int e = blockIdx.x * 256 + threadIdx.x;
  if (e < EE) {
    int s1 = ei[e], d1 = ei[EE + e];
    int p1 = atomicAdd(&cur[d1], 1);
    adj1[p1] = s1;                      // conv1: message source = row0
    int p2 = atomicAdd(&cur[NN + s1], 1);
    adj2[p2] = d1;                      // conv2: message source = row1
  }
}

// ------------------------- mega GEMM: h8(fp8) = x@[W1|W2]^T + fused a_s/a_d
// 1D grid 1256 = 157 bm x 8 bn, XCD-chunked.
__global__ __launch_bounds__(256) void k_gemm_big(const u16* __restrict__ A,
                                                  const u16* __restrict__ Bt,
                                                  const float* __restrict__ as1,
                                                  const float* __restrict__ ad1,
                                                  const float* __restrict__ as2,
                                                  const float* __restrict__ ad2,
                                                  u8* __restrict__ h8,
                                                  float* __restrict__ a_sA,
                                                  float* __restrict__ a_dA) {
  __shared__ u16 As[128 * 64];
  __shared__ u16 Bs[128 * 64];
  const int hw = blockIdx.x;
  const int logical = (hw & 7) * 157 + (hw >> 3);
  const int bm = (logical >> 3) * 128, bn = logical & 7;
  const int t = threadIdx.x;
  const int lane = t & 63, wave = t >> 6;
  const int wr = (wave >> 1) * 64, wc = (wave & 1) * 64;
  const int l15 = lane & 15, l4 = lane >> 4;
  const int rloc = lane >> 3;
  const int kc_src = (lane & 7) ^ rloc;
  const int K = FIN;

  f32x4 acc[4][4] = {};
  for (int k0 = 0; k0 < K; k0 += 64) {
    __syncthreads();
#pragma unroll
    for (int q = 0; q < 4; ++q) {
      const int rblk = q * 4 + wave;
      const int r = rblk * 8 + rloc;
      gload16(A + (size_t)(bm + r) * K + k0 + kc_src * 8, As + rblk * 512);
      gload16(Bt + (size_t)(bn * 128 + r) * K + k0 + kc_src * 8, Bs + rblk * 512);
    }
    __syncthreads();
#pragma unroll
    for (int kh = 0; kh < 2; ++kh) {
      const int kc = kh * 4 + l4;
      short8v af[4], bfr[4];
#pragma unroll
      for (int i = 0; i < 4; ++i) {
        int row = wr + i * 16 + l15;
        af[i] = *(const short8v*)(As + row * 64 + (kc ^ (row & 7)) * 8);
      }
#pragma unroll
      for (int j = 0; j < 4; ++j) {
        int row = wc + j * 16 + l15;
        bfr[j] = *(const short8v*)(Bs + row * 64 + (kc ^ (row & 7)) * 8);
      }
#pragma unroll
      for (int i = 0; i < 4; ++i)
#pragma unroll
        for (int j = 0; j < 4; ++j)
          acc[i][j] = __builtin_amdgcn_mfma_f32_16x16x32_bf16(af[i], bfr[j], acc[i][j], 0, 0, 0);
    }
  }

  const int conv = bn >> 2;
  // h8 writes (fp8 e4m3, 1 byte per element)
#pragma unroll
  for (int i = 0; i < 4; ++i)
#pragma unroll
    for (int j = 0; j < 4; ++j)
#pragma unroll
      for (int r = 0; r < 4; ++r) {
        int row = bm + wr + i * 16 + l4 * 4 + r;
        if (row >= NN) continue;
        int colb = bn * 128 + wc + j * 16 + l15;
        float v = acc[i][j][r];
        unsigned e8 = __builtin_amdgcn_cvt_pk_fp8_f32(v, v, 0, false);
        h8[(size_t)row * H8W + colb] = (u8)e8;
      }

  // fused a_s/a_d from f32 accumulators
  float asv[4], adv[4];
#pragma unroll
  for (int j = 0; j < 4; ++j) {
    int lc = (bn & 3) * 128 + wc + j * 16 + l15;
    int hh = lc >> 5, c = lc & 31;
    asv[j] = (conv ? as2 : as1)[hh * CC + c];
    adv[j] = (conv ? ad2 : ad1)[hh * CC + c];
  }
  const int hA = (bn & 3) * 4 + (wc >> 5);
  float* aS = a_sA + (size_t)conv * NN * HH;
  float* aD = a_dA + (size_t)conv * NN * HH;
#pragma unroll
  for (int i = 0; i < 4; ++i)
#pragma unroll
    for (int r = 0; r < 4; ++r) {
      float sAs = acc[i][0][r] * asv[0] + acc[i][1][r] * asv[1];
      float sAd = acc[i][0][r] * adv[0] + acc[i][1][r] * adv[1];
      float sBs = acc[i][2][r] * asv[2] + acc[i][3][r] * asv[3];
      float sBd = acc[i][2][r] * adv[2] + acc[i][3][r] * adv[3];
#pragma unroll
      for (int m = 1; m < 16; m <<= 1) {
        sAs += __shfl_xor(sAs, m);
        sAd += __shfl_xor(sAd, m);
        sBs += __shfl_xor(sBs, m);
        sBd += __shfl_xor(sBd, m);
      }
      int row = bm + wr + i * 16 + l4 * 4 + r;
      if (l15 == 0 && row < NN) {
        *(float2*)(aS + (size_t)row * HH + hA) = make_float2(sAs, sBs);
        *(float2*)(aD + (size_t)row * HH + hA) = make_float2(sAd, sBd);
      }
    }
}

// --------------------------- self path: out3 = elu(elu(x@lin1+b)@lin2+b)
__global__ __launch_bounds__(256) void k_self(const u16* __restrict__ A,
                                              const u16* __restrict__ lt1,
                                              const u16* __restrict__ lt2,
                                              const float* __restrict__ lin1_b,
                                              const float* __restrict__ lin2_b,
                                              float* __restrict__ outp) {
  __shared__ u16 smem[128 * 136];
  u16* As = smem;
  u16* Bs = smem + 128 * 64;
  const int t = threadIdx.x;
  const int lane = t & 63, wave = t >> 6;
  const int wr = (wave >> 1) * 64, wc = (wave & 1) * 64;
  const int bm = blockIdx.x * 128;
  const int l15 = lane & 15, l4 = lane >> 4;
  const int rloc = lane >> 3;
  const int kc_src = (lane & 7) ^ rloc;
  const int K = FIN;

  f32x4 acc[4][4] = {};
  for (int k0 = 0; k0 < K; k0 += 64) {
    __syncthreads();
#pragma unroll
    for (int q = 0; q < 4; ++q) {
      const int rblk = q * 4 + wave;
      const int r = rblk * 8 + rloc;
      gload16(A + (size_t)(bm + r) * K + k0 + kc_src * 8, As + rblk * 512);
      gload16(lt1 + (size_t)r * K + k0 + kc_src * 8, Bs + rblk * 512);
    }
    __syncthreads();
#pragma unroll
    for (int kh = 0; kh < 2; ++kh) {
      const int kc = kh * 4 + l4;
      short8v af[4], bfr[4];
#pragma unroll
      for (int i = 0; i < 4; ++i) {
        int row = wr + i * 16 + l15;
        af[i] = *(const short8v*)(As + row * 64 + (kc ^ (row & 7)) * 8);
      }
#pragma unroll
      for (int j = 0; j < 4; ++j) {
        int row = wc + j * 16 + l15;
        bfr[j] = *(const short8v*)(Bs + row * 64 + (kc ^ (row & 7)) * 8);
      }
#pragma unroll
      for (int i = 0; i < 4; ++i)
#pragma unroll
        for (int j = 0; j < 4; ++j)
          acc[i][j] = __builtin_amdgcn_mfma_f32_16x16x32_bf16(af[i], bfr[j], acc[i][j], 0, 0, 0);
    }
  }
  __syncthreads();
#pragma unroll
  for (int i = 0; i < 4; ++i)
#pragma unroll
    for (int j = 0; j < 4; ++j)
#pragma unroll
      for (int r = 0; r < 4; ++r) {
        int row = wr + i * 16 + l4 * 4 + r;
        int col = wc + j * 16 + l15;
        float v = acc[i][j][r] + lin1_b[col];
        v = v > 0.f ? v : (expf(v) - 1.f);
        smem[row * 136 + col] = f2bf(v);
      }
  __syncthreads();
  f32x4 acc2[2][2] = {};
#pragma unroll
  for (int kk = 0; kk < 4; ++kk) {
    short8v af[2], bfr[2];
#pragma unroll
    for (int i = 0; i < 2; ++i)
      af[i] = *(const short8v*)(smem + (wave * 32 + i * 16 + l15) * 136 + kk * 32 + l4 * 8);
#pragma unroll
    for (int j = 0; j < 2; ++j)
      bfr[j] = *(const short8v*)(lt2 + (size_t)(j * 16 + l15) * 128 + kk * 32 + l4 * 8);
#pragma unroll
    for (int i = 0; i < 2; ++i)
#pragma unroll
      for (int j = 0; j < 2; ++j)
        acc2[i][j] = __builtin_amdgcn_mfma_f32_16x16x32_bf16(af[i], bfr[j], acc2[i][j], 0, 0, 0);
  }
#pragma unroll
  for (int i = 0; i < 2; ++i)
#pragma unroll
    for (int j = 0; j < 2; ++j)
#pragma unroll
      for (int r = 0; r < 4; ++r) {
        int row = bm + wave * 32 + i * 16 + l4 * 4 + r;
        int col = j * 16 + l15;
        if (row < NN) {
          float v = acc2[i][j][r] + lin2_b[col];
          v = v > 0.f ? v : (expf(v) - 1.f);
          outp[(size_t)row * OUTC + col] = v;
        }
      }
}

// ---------------------- fused softmax + aggregation, both convs, independent waves
// grid 10000 x 256; wave w of block b handles gid = b*4+w (conv = gid>=NN).
// Phase B reads fp8 h8 (8 bytes/lane/edge = half of bf16).
__global__ __launch_bounds__(256) void k_edge(const int* __restrict__ adj1,
                                              const int* __restrict__ off1,
                                              const int* __restrict__ adj2,
                                              const int* __restrict__ off2,
                                              const float* __restrict__ a_sA,
                                              const float* __restrict__ a_dA,
                                              const u8* __restrict__ h8,
                                              const float* __restrict__ b1,
                                              const float* __restrict__ b2,
                                              float* __restrict__ out) {
  __shared__ float exs[4][CAPD * 16];
  const int wv = threadIdx.x >> 6, lane = threadIdx.x & 63;
  const int gid = blockIdx.x * 4 + wv;
  const int conv = gid >= NN;
  const int node = gid - conv * NN;
  const int* __restrict__ adj = conv ? adj2 : adj1;
  const int* __restrict__ off = conv ? off2 : off1;
  const float* __restrict__ a_s = a_sA + (size_t)conv * NN * HH;
  const float* __restrict__ a_d = a_dA + (size_t)conv * NN * HH;
  const u8* __restrict__ hbase = h8 + conv * HC;
  const float* __restrict__ bias = conv ? b2 : b1;
  float* __restrict__ outp = out + (size_t)conv * NN * OUTC;
  float* exw = exs[wv];
  const int e0 = off[node], e1 = off[node + 1];
  const int deg = e1 - e0;

  float mx = -INFINITY, sum = 0.f;
  float adh_a;
  {  // ---- phase A: alpha -> LDS (f32), wave-reduce max & denom
    const int ha = lane & 15, j = lane >> 4;
    adh_a = a_d[node * HH + ha];
    for (int p = e0 + j; p < e1; p += 4) {
      int s = adj[p];
      float a = a_s[s * HH + ha] + adh_a;
      a = a > 0.f ? a : 0.2f * a;
      int q = p - e0;
      if (q < CAPD) exw[q * 16 + ha] = a;
      mx = fmaxf(mx, a);
    }
    mx = fmaxf(mx, __shfl_xor(mx, 16));
    mx = fmaxf(mx, __shfl_xor(mx, 32));
    for (int p = e0 + j; p < e1; p += 4) {
      int q = p - e0;
      float a;
      if (q < CAPD) {
        a = exw[q * 16 + ha];
      } else {
        int s = adj[p];
        a = a_s[s * HH + ha] + adh_a;
        a = a > 0.f ? a : 0.2f * a;
      }
      float e = __expf(a - mx);
      if (q < CAPD) exw[q * 16 + ha] = e;
      sum += e;
    }
    sum += __shfl_xor(sum, 16);
    sum += __shfl_xor(sum, 32);
  }
  __builtin_amdgcn_wave_barrier();
  __asm__ volatile("" ::: "memory");

  // ---- phase B: h-gather aggregation (h = lane>>2, 8 channels/lane, fp8)
  const int h = lane >> 2, coff = (lane & 3) * 8;
  const float mxh = __shfl(mx, h);
  const float ivh = __shfl(1.f / (sum + 1e-16f), h);
  float acc0[8] = {}, acc1[8] = {};
  int p = e0;
  if (deg <= CAPD) {
    for (; p + 4 <= e1; p += 4) {
      int q = p - e0;
      int s0 = adj[p], s1 = adj[p + 1], s2 = adj[p + 2], s3 = adj[p + 3];
      float w0 = exw[q * 16 + h];
      float w1 = exw[(q + 1) * 16 + h];
      float w2 = exw[(q + 2) * 16 + h];
      float w3 = exw[(q + 3) * 16 + h];
      uint2 h0 = *(const uint2*)(hbase + (size_t)s0 * H8W + h * CC + coff);
      uint2 h1 = *(const uint2*)(hbase + (size_t)s1 * H8W + h * CC + coff);
      uint2 h2 = *(const uint2*)(hbase + (size_t)s2 * H8W + h * CC + coff);
      uint2 h3 = *(const uint2*)(hbase + (size_t)s3 * H8W + h * CC + coff);
      fp8x8_fma(h0, w0, acc0);
      fp8x8_fma(h1, w1, acc1);
      fp8x8_fma(h2, w2, acc0);
      fp8x8_fma(h3, w3, acc1);
    }
    for (; p < e1; ++p) {
      int q = p - e0;
      float w0 = exw[q * 16 + h];
      uint2 h0 = *(const uint2*)(hbase + (size_t)adj[p] * H8W + h * CC + coff);
      fp8x8_fma(h0, w0, acc0);
    }
  } else {  // rare: deg > CAPD, recompute weights past capacity
    const float adh = a_d[node * HH + h];
    for (; p < e1; ++p) {
      int q = p - e0;
      int s0 = adj[p];
      float w0;
      if (q < CAPD) {
        w0 = exw[q * 16 + h];
      } else {
        float a = a_s[s0 * HH + h] + adh;
        a = a > 0.f ? a : 0.2f * a;
        w0 = __expf(a - mxh);
      }
      uint2 h0 = *(const uint2*)(hbase + (size_t)s0 * H8W + h * CC + coff);
      fp8x8_fma(h0, w0, acc0);
    }
  }
  float accf[8];
#pragma unroll
  for (int i = 0; i < 8; ++i) accf[i] = (acc0[i] + acc1[i]) * ivh;
#pragma unroll
  for (int mk = 4; mk <= 32; mk <<= 1)
#pragma unroll
    for (int i = 0; i < 8; ++i) accf[i] += __shfl_xor(accf[i], mk);
  if (lane < 4) {
#pragma unroll
    for (int i = 0; i < 8; ++i) {
      int c = coff + i;
      float v = accf[i] * (1.f / 16.f) + bias[c];
      v = v > 0.f ? v : (expf(v) - 1.f);
      outp[(size_t)node * OUTC + c] = v;
    }
  }
}

// ---------------------------------------------------------------- launch
extern "C" void kernel_launch(void* const* d_in, const int* in_sizes, int n_in,
                              void* d_out, int out_size, void* d_ws, size_t ws_size,
                              hipStream_t stream) {
  const float* x = (const float*)d_in[0];
  const int* ei = (const int*)d_in[1];
  const float* W1 = (const float*)d_in[2];
  const float* att_src1 = (const float*)d_in[3];
  const float* att_dst1 = (const float*)d_in[4];
  const float* b1 = (const float*)d_in[5];
  const float* W2 = (const float*)d_in[6];
  const float* att_src2 = (const float*)d_in[7];
  const float* att_dst2 = (const float*)d_in[8];
  const float* b2 = (const float*)d_in[9];
  const float* lin1_w = (const float*)d_in[10];
  const float* lin1_b = (const float*)d_in[11];
  const float* lin2_w = (const float*)d_in[12];
  const float* lin2_b = (const float*)d_in[13];
  float* out = (float*)d_out;  // [x_in | x_out | x_self], each N*32

  char* w = (char*)d_ws;
  u8* h8 = (u8*)w;          w += (size_t)NN * H8W;           // 20.48 MB fp8
  u16* x_bf = (u16*)w;      w += (size_t)NN * FIN * 2;       // 10.24 MB
  u16* wtc = (u16*)w;       w += (size_t)WT * FIN * 2;       // 0.52 MB
  u16* lt1 = (u16*)w;       w += (size_t)HIDN * FIN * 2;
  u16* lt2 = (u16*)w;       w += (size_t)OUTC * HIDN * 2;
  float* a_sA = (float*)w;  w += (size_t)2 * NN * HH * 4;    // 2.56 MB
  float* a_dA = (float*)w;  w += (size_t)2 * NN * HH * 4;
  int* off1 = (int*)w;      w += (size_t)(NN + 1) * 4;
  int* off2 = (int*)w;      w += (size_t)(NN + 1) * 4;
  int* cur = (int*)w;       w += (size_t)2 * NN * 4;
  int* adj1 = (int*)w;      w += (size_t)EE * 4;
  int* adj2 = (int*)w;      w += (size_t)EE * 4;

  const int EB = (EE + 255) / 256;  // 1563

  // CSR build + converts
  hipMemsetAsync(cur, 0, (size_t)2 * NN * 4, stream);
  k_prep_hist<<<3668 + EB, 256, 0, stream>>>(x, x_bf, W1, W2, wtc, lin1_w, lt1,
                                             lin2_w, lt2, ei, cur);
  k_scan<<<2, 1024, 0, stream>>>(cur, off1, off2);
  k_scatter<<<EB, 256, 0, stream>>>(ei, cur, adj1, adj2);

  // mega GEMM (h8 fp8 + fused a_s/a_d), then self path
  k_gemm_big<<<1256, 256, 0, stream>>>(x_bf, wtc, att_src1, att_dst1,
                                       att_src2, att_dst2, h8, a_sA, a_dA);
  k_self<<<157, 256, 0, stream>>>(x_bf, lt1, lt2, lin1_b, lin2_b,
                                  out + (size_t)2 * NN * OUTC);

  // fused softmax+aggregation, both convs
  k_edge<<<2 * (NN / 4), 256, 0, stream>>>(adj1, off1, adj2, off2, a_sA, a_dA,
                                           h8, b1, b2, out);
}

// Round 11
// 232.455 us; speedup vs baseline: 1.7405x; 1.1839x over previous
//
#include <hip/hip_runtime.h>
#include <math.h>

#define NN 20000
#define EE 400000
#define FIN 256
#define HH 16
#define CC 32
#define HC 512    // channels per conv
#define H8W 1024  // h8 row width in bytes (conv1 | conv2)
#define HIDN 128
#define OUTC 32
#define WT 1024   // wtc rows (W1^T | W2^T)

typedef unsigned short u16;
typedef unsigned char u8;
typedef __attribute__((ext_vector_type(8))) short short8v;
typedef __attribute__((ext_vector_type(4))) float f32x4;
typedef __attribute__((ext_vector_type(2))) float f32x2;

__device__ inline u16 f2bf(float f) {
  unsigned u = __builtin_bit_cast(unsigned, f);
  unsigned r = (u + 0x7fffu + ((u >> 16) & 1u)) >> 16;
  return (u16)r;
}
__device__ inline float bf2f(u16 b) {
  unsigned u = ((unsigned)b) << 16;
  return __builtin_bit_cast(float, u);
}

__device__ __forceinline__ void gload16(const u16* g, u16* l) {
  __builtin_amdgcn_global_load_lds(
      (const __attribute__((address_space(1))) unsigned int*)g,
      (__attribute__((address_space(3))) unsigned int*)l, 16, 0, 0);
}

// fp8 (e4m3) decode of 8 packed bytes -> fma into acc[0..8)
__device__ __forceinline__ void fp8x8_fma(uint2 hv, float w, float* acc) {
  f32x2 p;
  p = __builtin_amdgcn_cvt_pk_f32_fp8(hv.x, false);
  acc[0] = fmaf(w, p.x, acc[0]); acc[1] = fmaf(w, p.y, acc[1]);
  p = __builtin_amdgcn_cvt_pk_f32_fp8(hv.x, true);
  acc[2] = fmaf(w, p.x, acc[2]); acc[3] = fmaf(w, p.y, acc[3]);
  p = __builtin_amdgcn_cvt_pk_f32_fp8(hv.y, false);
  acc[4] = fmaf(w, p.x, acc[4]); acc[5] = fmaf(w, p.y, acc[5]);
  p = __builtin_amdgcn_cvt_pk_f32_fp8(hv.y, true);
  acc[6] = fmaf(w, p.x, acc[6]); acc[7] = fmaf(w, p.y, acc[7]);
}

// ------------------------------------------- merged converts + edge histogram
__global__ void k_prep_hist(const float* __restrict__ x, u16* __restrict__ xb,
                            const float* __restrict__ W1, const float* __restrict__ W2,
                            u16* __restrict__ wtc,
                            const float* __restrict__ L1, u16* __restrict__ lt1,
                            const float* __restrict__ L2, u16* __restrict__ lt2,
                            const int* __restrict__ ei, int* __restrict__ cur) {
  int b = blockIdx.x, t = threadIdx.x;
  if (b < 2500) {
    int i = b * 256 + t;
    float4 v0 = ((const float4*)x)[i * 2];
    float4 v1 = ((const float4*)x)[i * 2 + 1];
    short8v o;
    o[0] = (short)f2bf(v0.x); o[1] = (short)f2bf(v0.y);
    o[2] = (short)f2bf(v0.z); o[3] = (short)f2bf(v0.w);
    o[4] = (short)f2bf(v1.x); o[5] = (short)f2bf(v1.y);
    o[6] = (short)f2bf(v1.z); o[7] = (short)f2bf(v1.w);
    *(short8v*)(xb + (size_t)i * 8) = o;
  } else if (b < 3524) {
    int i = (b - 2500) * 256 + t;   // [1024][256]
    int n = i >> 8, k = i & 255;
    wtc[i] = f2bf(n < 512 ? W1[k * HC + n] : W2[k * HC + (n - 512)]);
  } else if (b < 3652) {
    int i = (b - 3524) * 256 + t;   // [128][256]
    int n = i >> 8, k = i & 255;
    lt1[i] = f2bf(L1[k * HIDN + n]);
  } else if (b < 3668) {
    int i = (b - 3652) * 256 + t;   // [32][128]
    int n = i >> 7, k = i & 127;
    lt2[i] = f2bf(L2[k * OUTC + n]);
  } else {
    int e = (b - 3668) * 256 + t;
    if (e < EE) {
      atomicAdd(&cur[ei[EE + e]], 1);       // conv1 aggregates at row1
      atomicAdd(&cur[NN + ei[e]], 1);       // conv2 aggregates at row0
    }
  }
}

__device__ void scan_one(int* cur, int* off, int* part) {
  const int t = threadIdx.x;
  const int CHK = 20;
  int base = t * CHK;
  int loc[CHK];
  int s = 0;
#pragma unroll
  for (int i = 0; i < CHK; ++i) {
    int idx = base + i;
    int v = (idx < NN) ? cur[idx] : 0;
    loc[i] = s;
    s += v;
  }
  part[t] = s;
  __syncthreads();
  for (int d = 1; d < 1024; d <<= 1) {
    int v2 = (t >= d) ? part[t - d] : 0;
    __syncthreads();
    part[t] += v2;
    __syncthreads();
  }
  int cbase = part[t] - s;
#pragma unroll
  for (int i = 0; i < CHK; ++i) {
    int idx = base + i;
    if (idx < NN) {
      int o = cbase + loc[i];
      off[idx] = o;
      cur[idx] = o;
    }
  }
  if (t == 1023) off[NN] = part[1023];
}

__global__ __launch_bounds__(1024) void k_scan(int* cur, int* off1, int* off2) {
  __shared__ int part[1024];
  if (blockIdx.x == 0) scan_one(cur, off1, part);
  else                 scan_one(cur + NN, off2, part);
}

__global__ void k_scatter(const int* __restrict__ ei, int* cur,
                          int* __restrict__ adj1, int* __restrict__ adj2) {
  int e = blockIdx.x * 256 + threadIdx.x;
  if (e < EE) {
    int s1 = ei[e], d1 = ei[EE + e];
    int p1 = atomicAdd(&cur[d1], 1);
    adj1[p1] = s1;                      // conv1: message source = row0
    int p2 = atomicAdd(&cur[NN + s1], 1);
    adj2[p2] = d1;                      // conv2: message source = row1
  }
}

// ------------------------- mega GEMM: h8(fp8) = x@[W1|W2]^T + fused a_s/a_d
// 1D grid 1256 = 157 bm x 8 bn, XCD-chunked.
__global__ __launch_bounds__(256) void k_gemm_big(const u16* __restrict__ A,
                                                  const u16* __restrict__ Bt,
                                                  const float* __restrict__ as1,
                                                  const float* __restrict__ ad1,
                                                  const float* __restrict__ as2,
                                                  const float* __restrict__ ad2,
                                                  u8* __restrict__ h8,
                                                  float* __restrict__ a_sA,
                                                  float* __restrict__ a_dA) {
  __shared__ u16 As[128 * 64];
  __shared__ u16 Bs[128 * 64];
  const int hw = blockIdx.x;
  const int logical = (hw & 7) * 157 + (hw >> 3);
  const int bm = (logical >> 3) * 128, bn = logical & 7;
  const int t = threadIdx.x;
  const int lane = t & 63, wave = t >> 6;
  const int wr = (wave >> 1) * 64, wc = (wave & 1) * 64;
  const int l15 = lane & 15, l4 = lane >> 4;
  const int rloc = lane >> 3;
  const int kc_src = (lane & 7) ^ rloc;
  const int K = FIN;

  f32x4 acc[4][4] = {};
  for (int k0 = 0; k0 < K; k0 += 64) {
    __syncthreads();
#pragma unroll
    for (int q = 0; q < 4; ++q) {
      const int rblk = q * 4 + wave;
      const int r = rblk * 8 + rloc;
      gload16(A + (size_t)(bm + r) * K + k0 + kc_src * 8, As + rblk * 512);
      gload16(Bt + (size_t)(bn * 128 + r) * K + k0 + kc_src * 8, Bs + rblk * 512);
    }
    __syncthreads();
#pragma unroll
    for (int kh = 0; kh < 2; ++kh) {
      const int kc = kh * 4 + l4;
      short8v af[4], bfr[4];
#pragma unroll
      for (int i = 0; i < 4; ++i) {
        int row = wr + i * 16 + l15;
        af[i] = *(const short8v*)(As + row * 64 + (kc ^ (row & 7)) * 8);
      }
#pragma unroll
      for (int j = 0; j < 4; ++j) {
        int row = wc + j * 16 + l15;
        bfr[j] = *(const short8v*)(Bs + row * 64 + (kc ^ (row & 7)) * 8);
      }
#pragma unroll
      for (int i = 0; i < 4; ++i)
#pragma unroll
        for (int j = 0; j < 4; ++j)
          acc[i][j] = __builtin_amdgcn_mfma_f32_16x16x32_bf16(af[i], bfr[j], acc[i][j], 0, 0, 0);
    }
  }

  const int conv = bn >> 2;
  // h8 writes (fp8 e4m3, 1 byte per element)
#pragma unroll
  for (int i = 0; i < 4; ++i)
#pragma unroll
    for (int j = 0; j < 4; ++j)
#pragma unroll
      for (int r = 0; r < 4; ++r) {
        int row = bm + wr + i * 16 + l4 * 4 + r;
        if (row >= NN) continue;
        int colb = bn * 128 + wc + j * 16 + l15;
        float v = acc[i][j][r];
        unsigned e8 = __builtin_amdgcn_cvt_pk_fp8_f32(v, v, 0, false);
        h8[(size_t)row * H8W + colb] = (u8)e8;
      }

  // fused a_s/a_d from f32 accumulators
  float asv[4], adv[4];
#pragma unroll
  for (int j = 0; j < 4; ++j) {
    int lc = (bn & 3) * 128 + wc + j * 16 + l15;
    int hh = lc >> 5, c = lc & 31;
    asv[j] = (conv ? as2 : as1)[hh * CC + c];
    adv[j] = (conv ? ad2 : ad1)[hh * CC + c];
  }
  const int hA = (bn & 3) * 4 + (wc >> 5);
  float* aS = a_sA + (size_t)conv * NN * HH;
  float* aD = a_dA + (size_t)conv * NN * HH;
#pragma unroll
  for (int i = 0; i < 4; ++i)
#pragma unroll
    for (int r = 0; r < 4; ++r) {
      float sAs = acc[i][0][r] * asv[0] + acc[i][1][r] * asv[1];
      float sAd = acc[i][0][r] * adv[0] + acc[i][1][r] * adv[1];
      float sBs = acc[i][2][r] * asv[2] + acc[i][3][r] * asv[3];
      float sBd = acc[i][2][r] * adv[2] + acc[i][3][r] * adv[3];
#pragma unroll
      for (int m = 1; m < 16; m <<= 1) {
        sAs += __shfl_xor(sAs, m);
        sAd += __shfl_xor(sAd, m);
        sBs += __shfl_xor(sBs, m);
        sBd += __shfl_xor(sBd, m);
      }
      int row = bm + wr + i * 16 + l4 * 4 + r;
      if (l15 == 0 && row < NN) {
        *(float2*)(aS + (size_t)row * HH + hA) = make_float2(sAs, sBs);
        *(float2*)(aD + (size_t)row * HH + hA) = make_float2(sAd, sBd);
      }
    }
}

// --------------------------- self path: out3 = elu(elu(x@lin1+b)@lin2+b)
__global__ __launch_bounds__(256) void k_self(const u16* __restrict__ A,
                                              const u16* __restrict__ lt1,
                                              const u16* __restrict__ lt2,
                                              const float* __restrict__ lin1_b,
                                              const float* __restrict__ lin2_b,
                                              float* __restrict__ outp) {
  __shared__ u16 smem[128 * 136];
  u16* As = smem;
  u16* Bs = smem + 128 * 64;
  const int t = threadIdx.x;
  const int lane = t & 63, wave = t >> 6;
  const int wr = (wave >> 1) * 64, wc = (wave & 1) * 64;
  const int bm = blockIdx.x * 128;
  const int l15 = lane & 15, l4 = lane >> 4;
  const int rloc = lane >> 3;
  const int kc_src = (lane & 7) ^ rloc;
  const int K = FIN;

  f32x4 acc[4][4] = {};
  for (int k0 = 0; k0 < K; k0 += 64) {
    __syncthreads();
#pragma unroll
    for (int q = 0; q < 4; ++q) {
      const int rblk = q * 4 + wave;
      const int r = rblk * 8 + rloc;
      gload16(A + (size_t)(bm + r) * K + k0 + kc_src * 8, As + rblk * 512);
      gload16(lt1 + (size_t)r * K + k0 + kc_src * 8, Bs + rblk * 512);
    }
    __syncthreads();
#pragma unroll
    for (int kh = 0; kh < 2; ++kh) {
      const int kc = kh * 4 + l4;
      short8v af[4], bfr[4];
#pragma unroll
      for (int i = 0; i < 4; ++i) {
        int row = wr + i * 16 + l15;
        af[i] = *(const short8v*)(As + row * 64 + (kc ^ (row & 7)) * 8);
      }
#pragma unroll
      for (int j = 0; j < 4; ++j) {
        int row = wc + j * 16 + l15;
        bfr[j] = *(const short8v*)(Bs + row * 64 + (kc ^ (row & 7)) * 8);
      }
#pragma unroll
      for (int i = 0; i < 4; ++i)
#pragma unroll
        for (int j = 0; j < 4; ++j)
          acc[i][j] = __builtin_amdgcn_mfma_f32_16x16x32_bf16(af[i], bfr[j], acc[i][j], 0, 0, 0);
    }
  }
  __syncthreads();
#pragma unroll
  for (int i = 0; i < 4; ++i)
#pragma unroll
    for (int j = 0; j < 4; ++j)
#pragma unroll
      for (int r = 0; r < 4; ++r) {
        int row = wr + i * 16 + l4 * 4 + r;
        int col = wc + j * 16 + l15;
        float v = acc[i][j][r] + lin1_b[col];
        v = v > 0.f ? v : (expf(v) - 1.f);
        smem[row * 136 + col] = f2bf(v);
      }
  __syncthreads();
  f32x4 acc2[2][2] = {};
#pragma unroll
  for (int kk = 0; kk < 4; ++kk) {
    short8v af[2], bfr[2];
#pragma unroll
    for (int i = 0; i < 2; ++i)
      af[i] = *(const short8v*)(smem + (wave * 32 + i * 16 + l15) * 136 + kk * 32 + l4 * 8);
#pragma unroll
    for (int j = 0; j < 2; ++j)
      bfr[j] = *(const short8v*)(lt2 + (size_t)(j * 16 + l15) * 128 + kk * 32 + l4 * 8);
#pragma unroll
    for (int i = 0; i < 2; ++i)
#pragma unroll
      for (int j = 0; j < 2; ++j)
        acc2[i][j] = __builtin_amdgcn_mfma_f32_16x16x32_bf16(af[i], bfr[j], acc2[i][j], 0, 0, 0);
  }
#pragma unroll
  for (int i = 0; i < 2; ++i)
#pragma unroll
    for (int j = 0; j < 2; ++j)
#pragma unroll
      for (int r = 0; r < 4; ++r) {
        int row = bm + wave * 32 + i * 16 + l4 * 4 + r;
        int col = j * 16 + l15;
        if (row < NN) {
          float v = acc2[i][j][r] + lin2_b[col];
          v = v > 0.f ? v : (expf(v) - 1.f);
          outp[(size_t)row * OUTC + col] = v;
        }
      }
}

// ---------------- single-pass online softmax+aggregation (no max subtraction:
// |alpha| <~ 3, exp(alpha) safe in f32; coef identical mathematically).
// grid 10000 x 256; wave w of block b handles gid = b*4+w (conv = gid>=NN).
// Each lane: head h = lane>>2, 8 channels; accumulates w=exp(leaky(alpha)) into
// den (its head, every edge) and w*h8 into acc. No LDS, no barrier, no fallback.
__global__ __launch_bounds__(256) void k_edge(const int* __restrict__ adj1,
                                              const int* __restrict__ off1,
                                              const int* __restrict__ adj2,
                                              const int* __restrict__ off2,
                                              const float* __restrict__ a_sA,
                                              const float* __restrict__ a_dA,
                                              const u8* __restrict__ h8,
                                              const float* __restrict__ b1,
                                              const float* __restrict__ b2,
                                              float* __restrict__ out) {
  const int wv = threadIdx.x >> 6, lane = threadIdx.x & 63;
  const int gid = blockIdx.x * 4 + wv;
  const int conv = gid >= NN;
  const int node = gid - conv * NN;
  const int* __restrict__ adj = conv ? adj2 : adj1;
  const int* __restrict__ off = conv ? off2 : off1;
  const float* __restrict__ a_s = a_sA + (size_t)conv * NN * HH;
  const float* __restrict__ a_d = a_dA + (size_t)conv * NN * HH;
  const u8* __restrict__ hbase = h8 + conv * HC;
  const float* __restrict__ bias = conv ? b2 : b1;
  float* __restrict__ outp = out + (size_t)conv * NN * OUTC;
  const int e0 = off[node], e1 = off[node + 1];

  const int h = lane >> 2, coff = (lane & 3) * 8;
  const float adh = a_d[node * HH + h];
  float acc0[8] = {}, acc1[8] = {};
  float den = 0.f;
  int p = e0;
  for (; p + 4 <= e1; p += 4) {
    int s0 = adj[p], s1 = adj[p + 1], s2 = adj[p + 2], s3 = adj[p + 3];
    float al0 = a_s[s0 * HH + h] + adh;
    float al1 = a_s[s1 * HH + h] + adh;
    float al2 = a_s[s2 * HH + h] + adh;
    float al3 = a_s[s3 * HH + h] + adh;
    al0 = al0 > 0.f ? al0 : 0.2f * al0;
    al1 = al1 > 0.f ? al1 : 0.2f * al1;
    al2 = al2 > 0.f ? al2 : 0.2f * al2;
    al3 = al3 > 0.f ? al3 : 0.2f * al3;
    float w0 = __expf(al0), w1 = __expf(al1), w2 = __expf(al2), w3 = __expf(al3);
    uint2 h0 = *(const uint2*)(hbase + (size_t)s0 * H8W + h * CC + coff);
    uint2 h1 = *(const uint2*)(hbase + (size_t)s1 * H8W + h * CC + coff);
    uint2 h2 = *(const uint2*)(hbase + (size_t)s2 * H8W + h * CC + coff);
    uint2 h3 = *(const uint2*)(hbase + (size_t)s3 * H8W + h * CC + coff);
    den += (w0 + w1) + (w2 + w3);
    fp8x8_fma(h0, w0, acc0);
    fp8x8_fma(h1, w1, acc1);
    fp8x8_fma(h2, w2, acc0);
    fp8x8_fma(h3, w3, acc1);
  }
  for (; p < e1; ++p) {
    int s0 = adj[p];
    float al0 = a_s[s0 * HH + h] + adh;
    al0 = al0 > 0.f ? al0 : 0.2f * al0;
    float w0 = __expf(al0);
    uint2 h0 = *(const uint2*)(hbase + (size_t)s0 * H8W + h * CC + coff);
    den += w0;
    fp8x8_fma(h0, w0, acc0);
  }
  const float ivh = (1.f / 16.f) / (den + 1e-16f);
  float accf[8];
#pragma unroll
  for (int i = 0; i < 8; ++i) accf[i] = (acc0[i] + acc1[i]) * ivh;
#pragma unroll
  for (int mk = 4; mk <= 32; mk <<= 1)
#pragma unroll
    for (int i = 0; i < 8; ++i) accf[i] += __shfl_xor(accf[i], mk);
  if (lane < 4) {
#pragma unroll
    for (int i = 0; i < 8; ++i) {
      int c = coff + i;
      float v = accf[i] + bias[c];
      v = v > 0.f ? v : (expf(v) - 1.f);
      outp[(size_t)node * OUTC + c] = v;
    }
  }
}

// ---------------------------------------------------------------- launch
extern "C" void kernel_launch(void* const* d_in, const int* in_sizes, int n_in,
                              void* d_out, int out_size, void* d_ws, size_t ws_size,
                              hipStream_t stream) {
  const float* x = (const float*)d_in[0];
  const int* ei = (const int*)d_in[1];
  const float* W1 = (const float*)d_in[2];
  const float* att_src1 = (const float*)d_in[3];
  const float* att_dst1 = (const float*)d_in[4];
  const float* b1 = (const float*)d_in[5];
  const float* W2 = (const float*)d_in[6];
  const float* att_src2 = (const float*)d_in[7];
  const float* att_dst2 = (const float*)d_in[8];
  const float* b2 = (const float*)d_in[9];
  const float* lin1_w = (const float*)d_in[10];
  const float* lin1_b = (const float*)d_in[11];
  const float* lin2_w = (const float*)d_in[12];
  const float* lin2_b = (const float*)d_in[13];
  float* out = (float*)d_out;  // [x_in | x_out | x_self], each N*32

  char* w = (char*)d_ws;
  u8* h8 = (u8*)w;          w += (size_t)NN * H8W;           // 20.48 MB fp8
  u16* x_bf = (u16*)w;      w += (size_t)NN * FIN * 2;       // 10.24 MB
  u16* wtc = (u16*)w;       w += (size_t)WT * FIN * 2;       // 0.52 MB
  u16* lt1 = (u16*)w;       w += (size_t)HIDN * FIN * 2;
  u16* lt2 = (u16*)w;       w += (size_t)OUTC * HIDN * 2;
  float* a_sA = (float*)w;  w += (size_t)2 * NN * HH * 4;    // 2.56 MB
  float* a_dA = (float*)w;  w += (size_t)2 * NN * HH * 4;
  int* off1 = (int*)w;      w += (size_t)(NN + 1) * 4;
  int* off2 = (int*)w;      w += (size_t)(NN + 1) * 4;
  int* cur = (int*)w;       w += (size_t)2 * NN * 4;
  int* adj1 = (int*)w;      w += (size_t)EE * 4;
  int* adj2 = (int*)w;      w += (size_t)EE * 4;

  const int EB = (EE + 255) / 256;  // 1563

  // CSR build + converts
  hipMemsetAsync(cur, 0, (size_t)2 * NN * 4, stream);
  k_prep_hist<<<3668 + EB, 256, 0, stream>>>(x, x_bf, W1, W2, wtc, lin1_w, lt1,
                                             lin2_w, lt2, ei, cur);
  k_scan<<<2, 1024, 0, stream>>>(cur, off1, off2);
  k_scatter<<<EB, 256, 0, stream>>>(ei, cur, adj1, adj2);

  // mega GEMM (h8 fp8 + fused a_s/a_d), then self path
  k_gemm_big<<<1256, 256, 0, stream>>>(x_bf, wtc, att_src1, att_dst1,
                                       att_src2, att_dst2, h8, a_sA, a_dA);
  k_self<<<157, 256, 0, stream>>>(x_bf, lt1, lt2, lin1_b, lin2_b,
                                  out + (size_t)2 * NN * OUTC);

  // single-pass softmax+aggregation, both convs
  k_edge<<<2 * (NN / 4), 256, 0, stream>>>(adj1, off1, adj2, off2, a_sA, a_dA,
                                           h8, b1, b2, out);
}